// Round 3
// baseline (267.414 us; speedup 1.0000x reference)
//
#include <hip/hip_runtime.h>

// Problem: adjacency_full[i, neighbor_indices[i,k]] = adjacency_values[i,k]
// over a zeroed [N,N] fp32 matrix. N=8192, K=64.
//
// Fused zero+scatter, no LDS staging:
//   - each block owns one row; zeroes it with dependency-free float4 stores
//     (same stream shape as the 6.6 TB/s rocclr fill kernel)
//   - __syncthreads() drains vmcnt -> zero stores are at L2 (coherence point)
//   - 64 lanes overwrite scattered positions; lines are still dirty in this
//     XCD's L2 so the scatter adds no HBM traffic (unlike split memset+scatter,
//     where eviction forces an HBM RMW per scattered store)

constexpr int N_PATCH = 8192;
constexpr int K_NB = 64;
constexpr int BLOCK = 256;
constexpr int VEC_ITERS = N_PATCH / 4 / BLOCK;  // 8 float4 stores per thread

__global__ __launch_bounds__(BLOCK)
void fill_scatter_kernel(const float* __restrict__ vals,
                         const int* __restrict__ idx,
                         float* __restrict__ out) {
    const int r = blockIdx.x;
    const int t = threadIdx.x;

    // Issue the scatter-operand loads early (one wave); latency hidden by the
    // zero-store stream below.
    int c = 0;
    float v = 0.f;
    if (t < K_NB) {
        const int base = r * K_NB + t;
        c = idx[base];
        v = vals[base];
    }

    // Zero the row: pure streaming stores, no load/LDS dependency.
    float4* outv = reinterpret_cast<float4*>(out + (size_t)r * N_PATCH);
    const float4 z = make_float4(0.f, 0.f, 0.f, 0.f);
#pragma unroll
    for (int i = 0; i < VEC_ITERS; ++i)
        outv[t + i * BLOCK] = z;

    // Barrier drains vmcnt(0): all zero stores reach L2 before any overwrite.
    __syncthreads();

    if (t < K_NB)
        out[(size_t)r * N_PATCH + c] = v;
}

extern "C" void kernel_launch(void* const* d_in, const int* in_sizes, int n_in,
                              void* d_out, int out_size, void* d_ws, size_t ws_size,
                              hipStream_t stream) {
    const float* vals = (const float*)d_in[0];   // adjacency_values [N,K] fp32
    const int* idx = (const int*)d_in[1];        // neighbor_indices [N,K] int32
    float* out = (float*)d_out;                  // [N,N] fp32

    fill_scatter_kernel<<<N_PATCH, BLOCK, 0, stream>>>(vals, idx, out);
}